// Round 5
// baseline (358.743 us; speedup 1.0000x reference)
//
#include <hip/hip_runtime.h>
#include <hip/hip_bf16.h>

#define B_   4
#define H_   16
#define SEQ  2048
#define DH   64
#define BM   128
#define BN   64
#define NBH  (B_ * H_)
#define NELEM (NBH * SEQ * DH)   // 8388608 elements per tensor

typedef __bf16 bf16x8 __attribute__((ext_vector_type(8)));
typedef float  f32x4  __attribute__((ext_vector_type(4)));
typedef unsigned short u16x8 __attribute__((ext_vector_type(8)));
typedef unsigned short u16x4 __attribute__((ext_vector_type(4)));

__device__ __forceinline__ unsigned short f2bu(float x) {
    __hip_bfloat16 h = __float2bfloat16(x);
    return __builtin_bit_cast(unsigned short, h);
}

// ---------- fused prepass: K fp32->bf16 (same layout) + V fp32->bf16 transposed ----------
__global__ __launch_bounds__(256)
void prep_kv(const float* __restrict__ K, const float* __restrict__ V,
             unsigned short* __restrict__ Kb, unsigned short* __restrict__ Vt) {
    __shared__ unsigned short tile[64 * 72];
    const int bh = blockIdx.y;
    const int s0 = blockIdx.x * 64;
    const int t  = threadIdx.x;

    { // K convert: 64 rows x 64 cols contiguous, 16B stores
        const float* Ki = K + (size_t)bh * SEQ * DH + (size_t)s0 * DH;
        unsigned short* Ko = Kb + (size_t)bh * SEQ * DH + (size_t)s0 * DH;
        for (int jj = 0; jj < 2; ++jj) {
            const int e = (jj * 256 + t) * 8;
            const float4 a = *reinterpret_cast<const float4*>(Ki + e);
            const float4 b = *reinterpret_cast<const float4*>(Ki + e + 4);
            u16x8 u;
            u[0] = f2bu(a.x); u[1] = f2bu(a.y); u[2] = f2bu(a.z); u[3] = f2bu(a.w);
            u[4] = f2bu(b.x); u[5] = f2bu(b.y); u[6] = f2bu(b.z); u[7] = f2bu(b.w);
            *reinterpret_cast<u16x8*>(Ko + e) = u;
        }
    }

    const float* Vb = V + (size_t)bh * SEQ * DH + (size_t)s0 * DH;
    unsigned short* Vo = Vt + (size_t)bh * DH * SEQ;
    {
        const int sl = t >> 2, d0 = (t & 3) * 16;
        for (int c = 0; c < 4; ++c) {
            const float4 v = *reinterpret_cast<const float4*>(Vb + sl * DH + d0 + c * 4);
            u16x4 u; u[0] = f2bu(v.x); u[1] = f2bu(v.y); u[2] = f2bu(v.z); u[3] = f2bu(v.w);
            *reinterpret_cast<u16x4*>(&tile[sl * 72 + d0 + c * 4]) = u;
        }
    }
    __syncthreads();
    { // transposed store: each lane 2x16B contiguous
        const int d = t >> 2, sc0 = (t & 3) * 16;
        for (int c = 0; c < 2; ++c) {
            const int s = sc0 + c * 8;
            u16x8 u;
#pragma unroll
            for (int r = 0; r < 8; ++r) u[r] = tile[(s + r) * 72 + d];
            *reinterpret_cast<u16x8*>(Vo + (size_t)d * SEQ + s0 + s) = u;
        }
    }
}

// ---------- main flash-attention kernel ----------
// R10: ZERO LDS, ZERO BARRIERS. R7-R9 post-mortem: three structural changes
// (dbuf+swizzle, 2x occupancy, 1/2 LDS demand) all landed at 88-92us with
// MfmaUtil ~35% -> the limiter is dependency latency under the per-tile
// __syncthreads convoy, not any throughput pipe. At D=64 a K tile is 8KB =
// 32 VGPRs, so each wave stages K/V in REGISTERS via per-lane global loads:
//  - K double-buffered (issued at iter top, used next iter: ~full period of
//    latency cover); V single-buffered (issued at top, used ~600cyc later in
//    PV). Load order V-then-Knext => compiler's auto waitcnt is COUNTED
//    (QK: vmcnt(16), PV: vmcnt(8)) - T4 for free, no inline asm.
//  - alpha permutation folded into load addresses:
//    K row for (ks,m,l15) = 32*ks + 4*m + 8*(l15>>2) + (l15&3)
//    (identical to the HW-verified LDS slot mapping of R8/R9).
//  - no __syncthreads anywhere: waves fully self-paced, de-phase naturally,
//    MFMA/VALU/mem overlap across the 2 waves/SIMD.
//  - intra-block duplicate K/V reads (4 waves x same 16KB/tile) are L1 hits
//    (16KB << 32KB L1); L2 worst case bounds dur at ~60us.
//  - VGPR ~210 at launch_bounds(256,2): no spill headroom issue.
//    Spill alarm = WRITE_SIZE > 32768 KB.
__global__ __launch_bounds__(256, 2)
void fa_fwd(const float* __restrict__ Qg, const unsigned short* __restrict__ Kb,
            const unsigned short* __restrict__ Vtb, float* __restrict__ Og)
{
    const int tid  = threadIdx.x;
    const int lane = tid & 63;
    const int wave = tid >> 6;
    const int l15  = lane & 15;
    const int quad = lane >> 4;

    // XCD-bijective swizzle: xcd = bid&7 gets bh in [8*xcd, 8*xcd+8), qtile fastest
    const int bid   = blockIdx.x;          // 0..1023
    const int xcd   = bid & 7;
    const int jj    = bid >> 3;            // 0..127
    const int bh    = (xcd << 3) | (jj >> 4);
    const int qtile = jj & 15;

    const float*          Qb  = Qg  + (size_t)bh * SEQ * DH;
    const unsigned short* Kbh = Kb  + (size_t)bh * SEQ * DH;
    const unsigned short* Vbh = Vtb + (size_t)bh * DH * SEQ;
    float*                Ob  = Og  + (size_t)bh * SEQ * DH;

    const int qrow0 = qtile * BM + wave * 32;

    const float CS = 0.125f * 1.4426950408889634f; // folded into Qf

    // Q fragments (B-operand layout: n=l15, k=quad*8+j), PRE-SCALED by CS
    bf16x8 Qf[2][2];
#pragma unroll
    for (int rt = 0; rt < 2; ++rt) {
        const float* qsrc = Qb + (size_t)(qrow0 + rt * 16 + l15) * DH + quad * 8;
#pragma unroll
        for (int kt = 0; kt < 2; ++kt) {
            const float4 a = *reinterpret_cast<const float4*>(qsrc + kt * 32);
            const float4 b = *reinterpret_cast<const float4*>(qsrc + kt * 32 + 4);
            union { bf16x8 v; unsigned short u[8]; } tmp;
            tmp.u[0] = f2bu(a.x * CS); tmp.u[1] = f2bu(a.y * CS);
            tmp.u[2] = f2bu(a.z * CS); tmp.u[3] = f2bu(a.w * CS);
            tmp.u[4] = f2bu(b.x * CS); tmp.u[5] = f2bu(b.y * CS);
            tmp.u[6] = f2bu(b.z * CS); tmp.u[7] = f2bu(b.w * CS);
            Qf[rt][kt] = tmp.v;
        }
    }

    // splat-1.0 bf16 for row-sum MFMA
    bf16x8 ones;
    {
        union { bf16x8 v; unsigned short u[8]; } t;
        for (int i = 0; i < 8; ++i) t.u[i] = 0x3F80;
        ones = t.v;
    }
    const f32x4 fzero = {0.f, 0.f, 0.f, 0.f};

    f32x4 Oacc[2][4];
    f32x4 Lacc[2];
#pragma unroll
    for (int rt = 0; rt < 2; ++rt) {
        Lacc[rt] = fzero;
#pragma unroll
        for (int dt = 0; dt < 4; ++dt) Oacc[rt][dt] = fzero;
    }

    // ---- per-lane element offsets (iteration-invariant, static-indexed) ----
    // K frag kidx = ks*4 + m*2 + kt: row = 32*ks + 4*m + r15, col = quad*8 + kt*32
    // (r15 = 8*(l15>>2) + (l15&3); identical to the verified alpha' LDS mapping)
    const int r15 = 8 * (l15 >> 2) + (l15 & 3);
    int koff[8];
#pragma unroll
    for (int ks = 0; ks < 2; ++ks)
#pragma unroll
        for (int m = 0; m < 2; ++m)
#pragma unroll
            for (int kt = 0; kt < 2; ++kt)
                koff[ks * 4 + m * 2 + kt] =
                    (32 * ks + 4 * m + r15) * DH + quad * 8 + kt * 32;

    // V frag vidx = ks*4 + dt: Vt row d = dt*16 + l15, col = ks*32 + quad*8
    int voff[8];
#pragma unroll
    for (int ks = 0; ks < 2; ++ks)
#pragma unroll
        for (int dt = 0; dt < 4; ++dt)
            voff[ks * 4 + dt] = (dt * 16 + l15) * SEQ + ks * 32 + quad * 8;

    const unsigned short* kbase = Kbh;   // advanced by BN*DH per K tile
    const unsigned short* vbase = Vbh;   // advanced by BN per tile

    bf16x8 KA[8], KB[8], Vf[8];

#define KLOAD(DST, BASE) do {                                                  \
        _Pragma("unroll")                                                      \
        for (int x = 0; x < 8; ++x)                                            \
            DST[x] = *reinterpret_cast<const bf16x8*>((BASE) + koff[x]);       \
    } while (0)

#define VLOAD(DST, BASE) do {                                                  \
        _Pragma("unroll")                                                      \
        for (int x = 0; x < 8; ++x)                                            \
            DST[x] = *reinterpret_cast<const bf16x8*>((BASE) + voff[x]);       \
    } while (0)

// QK for one ks-group (kv rows [ks*32, ks*32+32)): 4 frags, 8 MFMA
#define QK_GRP(KSRC, KS, S) do {                                               \
        _Pragma("unroll")                                                      \
        for (int m = 0; m < 2; ++m) {                                          \
            const bf16x8 kf0 = KSRC[(KS) * 4 + m * 2 + 0];                     \
            const bf16x8 kf1 = KSRC[(KS) * 4 + m * 2 + 1];                     \
            _Pragma("unroll")                                                  \
            for (int rt = 0; rt < 2; ++rt) {                                   \
                S[rt][m] = __builtin_amdgcn_mfma_f32_16x16x32_bf16(kf0, Qf[rt][0], fzero,    0, 0, 0); \
                S[rt][m] = __builtin_amdgcn_mfma_f32_16x16x32_bf16(kf1, Qf[rt][1], S[rt][m], 0, 0, 0); \
            }                                                                  \
        }                                                                      \
    } while (0)

// exp2 + bf16 pack of one ks-group into af[*][KS] + L row-sum MFMA
#define SM_GRP(S, KS) do {                                                     \
        _Pragma("unroll")                                                      \
        for (int rt = 0; rt < 2; ++rt) {                                       \
            union { bf16x8 v; unsigned w[4]; } a;                              \
            _Pragma("unroll")                                                  \
            for (int m = 0; m < 2; ++m) {                                      \
                _Pragma("unroll")                                              \
                for (int rp = 0; rp < 2; ++rp) {                               \
                    const float p0 = __builtin_amdgcn_exp2f(S[rt][m][2 * rp    ]); \
                    const float p1 = __builtin_amdgcn_exp2f(S[rt][m][2 * rp + 1]); \
                    const unsigned u0 = __builtin_bit_cast(unsigned, p0) + 0x8000u; \
                    const unsigned u1 = __builtin_bit_cast(unsigned, p1) + 0x8000u; \
                    a.w[m * 2 + rp] = __builtin_amdgcn_perm(u1, u0, 0x07060302u); \
                }                                                              \
            }                                                                  \
            af[rt][KS] = a.v;                                                  \
            Lacc[rt] = __builtin_amdgcn_mfma_f32_16x16x32_bf16(a.v, ones, Lacc[rt], 0, 0, 0); \
        }                                                                      \
    } while (0)

// PV for one ks-group: 4 V frags, 8 MFMA
#define PV_GRP(VSRC, KS) do {                                                  \
        _Pragma("unroll")                                                      \
        for (int dt = 0; dt < 4; ++dt) {                                       \
            const bf16x8 bfr = VSRC[(KS) * 4 + dt];                            \
            _Pragma("unroll")                                                  \
            for (int rt = 0; rt < 2; ++rt)                                     \
                Oacc[rt][dt] = __builtin_amdgcn_mfma_f32_16x16x32_bf16(af[rt][KS], bfr, Oacc[rt][dt], 0, 0, 0); \
        }                                                                      \
    } while (0)

#define COMPUTE(KSRC, VSRC) do {                                               \
        f32x4 S[2][2];                                                         \
        bf16x8 af[2][2];                                                       \
        __builtin_amdgcn_s_setprio(1);                                         \
        QK_GRP(KSRC, 0, S);                                                    \
        __builtin_amdgcn_s_setprio(0);                                         \
        SM_GRP(S, 0);                                                          \
        __builtin_amdgcn_s_setprio(1);                                         \
        QK_GRP(KSRC, 1, S);                                                    \
        __builtin_amdgcn_s_setprio(0);                                         \
        SM_GRP(S, 1);                                                          \
        __builtin_amdgcn_s_setprio(1);                                         \
        PV_GRP(VSRC, 0);                                                       \
        PV_GRP(VSRC, 1);                                                       \
        __builtin_amdgcn_s_setprio(0);                                         \
    } while (0)

    // ---- barrier-free self-paced main loop over 32 KV tiles ----
    KLOAD(KA, kbase); kbase += BN * DH;          // K tile 0

#pragma unroll 1
    for (int it2 = 0; it2 < 16; ++it2) {
        // step A: tile 2*it2 from KA; prefetch K(2*it2+1) into KB
        VLOAD(Vf, vbase);                        // V(2*it2), used in PV below
        KLOAD(KB, kbase); kbase += BN * DH;      // K(2*it2+1) in flight
        COMPUTE(KA, Vf);
        vbase += BN;
        // step B: tile 2*it2+1 from KB; prefetch K(2*it2+2) into KA
        VLOAD(Vf, vbase);                        // V(2*it2+1)
        KLOAD(KA, kbase); kbase += BN * DH;      // K(2*it2+2) (last one OOB-benign: lands in Vt region)
        COMPUTE(KB, Vf);
        vbase += BN;
    }

#undef KLOAD
#undef VLOAD
#undef QK_GRP
#undef SM_GRP
#undef PV_GRP
#undef COMPUTE

    // ---- epilogue: Lacc rows already aligned with Oacc rows; no shuffles ----
#pragma unroll
    for (int rt = 0; rt < 2; ++rt) {
#pragma unroll
        for (int r = 0; r < 4; ++r) {
            const float inv = 1.0f / Lacc[rt][r];
            const int row = qrow0 + rt * 16 + quad * 4 + r;
            float* orow = Ob + (size_t)row * DH + l15;
#pragma unroll
            for (int dt = 0; dt < 4; ++dt)
                orow[dt * 16] = Oacc[rt][dt][r] * inv;
        }
    }
}

extern "C" void kernel_launch(void* const* d_in, const int* in_sizes, int n_in,
                              void* d_out, int out_size, void* d_ws, size_t ws_size,
                              hipStream_t stream) {
    const float* Q = (const float*)d_in[0];
    const float* K = (const float*)d_in[1];
    const float* V = (const float*)d_in[2];
    float* O = (float*)d_out;

    unsigned short* Kb = (unsigned short*)d_ws;   // 16 MB bf16 K
    unsigned short* Vt = Kb + (size_t)NELEM;      // 16 MB bf16 V^T

    prep_kv<<<dim3(SEQ / 64, NBH), 256, 0, stream>>>(K, V, Kb, Vt);
    fa_fwd<<<dim3((SEQ / BM) * NBH), dim3(256), 0, stream>>>(Q, Kb, Vt, O);
}

// Round 6
// 206.011 us; speedup vs baseline: 1.7414x; 1.7414x over previous
//
#include <hip/hip_runtime.h>
#include <hip/hip_bf16.h>

#define B_   4
#define H_   16
#define SEQ  2048
#define DH   64
#define BM   128
#define BN   64
#define NBH  (B_ * H_)
#define NELEM (NBH * SEQ * DH)   // 8388608 elements per tensor

typedef __bf16 bf16x8 __attribute__((ext_vector_type(8)));
typedef float  f32x4  __attribute__((ext_vector_type(4)));
typedef float  f32x16 __attribute__((ext_vector_type(16)));
typedef unsigned short u16x8 __attribute__((ext_vector_type(8)));
typedef unsigned short u16x4 __attribute__((ext_vector_type(4)));

__device__ __forceinline__ unsigned short f2bu(float x) {
    __hip_bfloat16 h = __float2bfloat16(x);
    return __builtin_bit_cast(unsigned short, h);
}

__device__ __forceinline__ void ld_lds16(const unsigned short* g, unsigned short* l) {
    __builtin_amdgcn_global_load_lds(
        (const __attribute__((address_space(1))) unsigned int*)(g),
        (__attribute__((address_space(3))) unsigned int*)(l), 16, 0, 0);
}

// ---------- fused prepass: K fp32->bf16 (same layout) + V fp32->bf16 transposed ----------
__global__ __launch_bounds__(256)
void prep_kv(const float* __restrict__ K, const float* __restrict__ V,
             unsigned short* __restrict__ Kb, unsigned short* __restrict__ Vt) {
    __shared__ unsigned short tile[64 * 72];
    const int bh = blockIdx.y;
    const int s0 = blockIdx.x * 64;
    const int t  = threadIdx.x;

    { // K convert: 64 rows x 64 cols contiguous, 16B stores
        const float* Ki = K + (size_t)bh * SEQ * DH + (size_t)s0 * DH;
        unsigned short* Ko = Kb + (size_t)bh * SEQ * DH + (size_t)s0 * DH;
        for (int jj = 0; jj < 2; ++jj) {
            const int e = (jj * 256 + t) * 8;
            const float4 a = *reinterpret_cast<const float4*>(Ki + e);
            const float4 b = *reinterpret_cast<const float4*>(Ki + e + 4);
            u16x8 u;
            u[0] = f2bu(a.x); u[1] = f2bu(a.y); u[2] = f2bu(a.z); u[3] = f2bu(a.w);
            u[4] = f2bu(b.x); u[5] = f2bu(b.y); u[6] = f2bu(b.z); u[7] = f2bu(b.w);
            *reinterpret_cast<u16x8*>(Ko + e) = u;
        }
    }

    const float* Vb = V + (size_t)bh * SEQ * DH + (size_t)s0 * DH;
    unsigned short* Vo = Vt + (size_t)bh * DH * SEQ;
    {
        const int sl = t >> 2, d0 = (t & 3) * 16;
        for (int c = 0; c < 4; ++c) {
            const float4 v = *reinterpret_cast<const float4*>(Vb + sl * DH + d0 + c * 4);
            u16x4 u; u[0] = f2bu(v.x); u[1] = f2bu(v.y); u[2] = f2bu(v.z); u[3] = f2bu(v.w);
            *reinterpret_cast<u16x4*>(&tile[sl * 72 + d0 + c * 4]) = u;
        }
    }
    __syncthreads();
    { // transposed store: each lane 2x16B contiguous
        const int d = t >> 2, sc0 = (t & 3) * 16;
        for (int c = 0; c < 2; ++c) {
            const int s = sc0 + c * 8;
            u16x8 u;
#pragma unroll
            for (int r = 0; r < 8; ++r) u[r] = tile[(s + r) * 72 + d];
            *reinterpret_cast<u16x8*>(Vo + (size_t)d * SEQ + s0 + s) = u;
        }
    }
}

// ---------- main flash-attention kernel ----------
// R11: 32x32x16 MFMA port of the R7 structure (best so far, 88.6us).
// R7-R10 established: staging/locality/occupancy/LDS-volume are NOT the
// limiter (all changed 2x with <5% effect); R10's register staging exposed
// raw memory latency (255us). Remaining lever: MFMA shape overhead.
//   - 16 MFMA/wave-tile (was 36): QK 2 C-tiles x4 chained + PV 2 halves x4.
//     Matrix work 541 vs 698 cyc/wave-tile; 55% fewer MFMA issue slots.
//   - S^T C-layout (col=lane&31=q): each lane owns ONE q-column ->
//     P feeds PV's A-operand in-register, L is a per-lane scalar add chain
//     (replaces 4 ones-MFMAs; epilogue = 1 shfl_xor + 16 bpermute).
//   - K rows staged with pi(r)=swap bits 2<->3 (within 32-row group) so
//     C-row kv indices line up with PV A-operand k-slots:
//       grow(s) = (s&3) + 4*((s>>3)&1) + 8*((s>>2)&1) + 16*((s>>4)&1) + 32*(s>>5)
//     (same derivation family as the HW-verified 16x16 alpha.)
//   - PV C cols = d -> O stores are coalesced 128B segments per instr.
//   - LDS layout/col-XOR-swizzles/dbuf loop/XCD swizzle identical to R7.
//   - SM(tile0) before QK(tile1): only one f32x16 S live -> ~130 VGPR peak,
//     launch_bounds(256,3) cap 170. Spill alarm = WRITE_SIZE > 32768 KB.
__global__ __launch_bounds__(256, 3)
void fa_fwd(const float* __restrict__ Qg, const unsigned short* __restrict__ Kb,
            const unsigned short* __restrict__ Vtb, float* __restrict__ Og)
{
    __shared__ __attribute__((aligned(16))) unsigned short smem[16384]; // 32 KB, 2 bufs

    const int tid  = threadIdx.x;
    const int lane = tid & 63;
    const int wave = tid >> 6;
    const int l31  = lane & 31;
    const int hi   = lane >> 5;
    const int l7   = lane & 7;

    // XCD-bijective swizzle: xcd = bid&7 gets bh in [8*xcd, 8*xcd+8), qtile fastest
    const int bid   = blockIdx.x;          // 0..1023
    const int xcd   = bid & 7;
    const int jj    = bid >> 3;            // 0..127
    const int bh    = (xcd << 3) | (jj >> 4);
    const int qtile = jj & 15;

    const float*          Qb  = Qg  + (size_t)bh * SEQ * DH;
    const unsigned short* Kbh = Kb  + (size_t)bh * SEQ * DH;
    const unsigned short* Vbh = Vtb + (size_t)bh * DH * SEQ;
    float*                Ob  = Og  + (size_t)bh * SEQ * DH;

    const int qrow0 = qtile * BM + wave * 32;

    const float CS = 0.125f * 1.4426950408889634f; // folded into Qf

    // Q fragments, 32x32x16 B-operand: col q = l31, k = 16*kt + 8*hi + j
    bf16x8 Qf[4];
#pragma unroll
    for (int kt = 0; kt < 4; ++kt) {
        const float* qsrc = Qb + (size_t)(qrow0 + l31) * DH + kt * 16 + hi * 8;
        const float4 a = *reinterpret_cast<const float4*>(qsrc);
        const float4 b = *reinterpret_cast<const float4*>(qsrc + 4);
        union { bf16x8 v; unsigned short u[8]; } tmp;
        tmp.u[0] = f2bu(a.x * CS); tmp.u[1] = f2bu(a.y * CS);
        tmp.u[2] = f2bu(a.z * CS); tmp.u[3] = f2bu(a.w * CS);
        tmp.u[4] = f2bu(b.x * CS); tmp.u[5] = f2bu(b.y * CS);
        tmp.u[6] = f2bu(b.z * CS); tmp.u[7] = f2bu(b.w * CS);
        Qf[kt] = tmp.v;
    }

    const f32x16 z16 = {0.f,0.f,0.f,0.f, 0.f,0.f,0.f,0.f,
                        0.f,0.f,0.f,0.f, 0.f,0.f,0.f,0.f};

    f32x16 OA = z16, OB = z16;   // O[q][d], halves d 0-31 / 32-63
    float Lp0 = 0.f, Lp1 = 0.f;  // per-lane partial row-sums (q = l31, hi half)

    // staging: global source pointers (bumped per tile) + LDS dest offsets
    const unsigned short* kp[2];
    const unsigned short* vp[2];
    int koff_st[2], voff_st[2];
    for (int i = 0; i < 2; ++i) {
        const int beta = i * 256 + tid;
        { // K: pi-permuted row (bits 2<->3 of 32-group), swizzled col block
            const int s    = beta >> 3;            // LDS row 0..63
            const int b    = beta & 7;
            const int gnat = b ^ (s & 7);
            const int grow = (s & 3) + 4 * ((s >> 3) & 1) + 8 * ((s >> 2) & 1)
                           + 16 * ((s >> 4) & 1) + 32 * (s >> 5);   // pi64
            kp[i]  = Kbh + (size_t)grow * DH + gnat * 8;
        }
        { // V: natural d-row, swizzled col block
            const int d = beta >> 3;               // 0..63
            const int g = (beta & 7) ^ (d & 7);
            vp[i]  = Vbh + (size_t)d * SEQ + g * 8;
        }
        koff_st[i] = (i * 256 + wave * 64) * 8;           // wave-uniform
        voff_st[i] = 4096 + (i * 256 + wave * 64) * 8;    // wave-uniform
    }

    // LDS read offsets (shorts), shared by K (c=kt) and V (c=m):
    // row = l31 (+32*T via immediate), col block = (2c+hi) ^ l7
    int rdoff[4];
#pragma unroll
    for (int c = 0; c < 4; ++c)
        rdoff[c] = l31 * 64 + ((((c << 1) | hi) ^ l7) << 3);

#define STAGE(BUF) do {                                                        \
        _Pragma("unroll")                                                      \
        for (int i = 0; i < 2; ++i) {                                          \
            ld_lds16(kp[i], smem + (BUF) * 8192 + koff_st[i]);                 \
            kp[i] += BN * DH;                                                  \
        }                                                                      \
        _Pragma("unroll")                                                      \
        for (int i = 0; i < 2; ++i) {                                          \
            ld_lds16(vp[i], smem + (BUF) * 8192 + voff_st[i]);                 \
            vp[i] += BN;                                                       \
        }                                                                      \
    } while (0)

// QK C-tile T (kv rows 32T..32T+31): 4 chained MFMA over k=64
#define QK_TILE(BUF, T, S) do {                                                \
        _Pragma("unroll")                                                      \
        for (int kt = 0; kt < 4; ++kt) {                                       \
            const bf16x8 kf = *reinterpret_cast<const bf16x8*>(                \
                &smem[(BUF) * 8192 + (T) * 2048 + rdoff[kt]]);                 \
            S = __builtin_amdgcn_mfma_f32_32x32x16_bf16(kf, Qf[kt],            \
                    (kt == 0) ? z16 : S, 0, 0, 0);                             \
        }                                                                      \
    } while (0)

// softmax of C-tile T: p = exp2(S); af[2T]=p[0..7], af[2T+1]=p[8..15]; L adds
#define SM_TILE(S, T) do {                                                     \
        float p[16];                                                           \
        _Pragma("unroll")                                                      \
        for (int r = 0; r < 16; ++r) p[r] = __builtin_amdgcn_exp2f(S[r]);      \
        _Pragma("unroll")                                                      \
        for (int c1 = 0; c1 < 2; ++c1) {                                       \
            union { bf16x8 v; unsigned w[4]; } a;                              \
            _Pragma("unroll")                                                  \
            for (int w = 0; w < 4; ++w) {                                      \
                const unsigned u0 = __builtin_bit_cast(unsigned, p[8*c1 + 2*w    ]) + 0x8000u; \
                const unsigned u1 = __builtin_bit_cast(unsigned, p[8*c1 + 2*w + 1]) + 0x8000u; \
                a.w[w] = __builtin_amdgcn_perm(u1, u0, 0x07060302u);           \
            }                                                                  \
            af[2 * (T) + c1] = a.v;                                            \
        }                                                                      \
        _Pragma("unroll")                                                      \
        for (int r = 0; r < 8; ++r)  Lp0 += p[r];                              \
        _Pragma("unroll")                                                      \
        for (int r = 8; r < 16; ++r) Lp1 += p[r];                              \
    } while (0)

// PV: A = af[m] (P frags, kv=16m+8hi+j), B = V^T LDS; both O halves interleaved
#define PV_ALL(BUF) do {                                                       \
        _Pragma("unroll")                                                      \
        for (int m = 0; m < 4; ++m) {                                          \
            const bf16x8 bv0 = *reinterpret_cast<const bf16x8*>(               \
                &smem[(BUF) * 8192 + 4096 + rdoff[m]]);                        \
            const bf16x8 bv1 = *reinterpret_cast<const bf16x8*>(               \
                &smem[(BUF) * 8192 + 4096 + 2048 + rdoff[m]]);                 \
            OA = __builtin_amdgcn_mfma_f32_32x32x16_bf16(af[m], bv0, OA, 0, 0, 0); \
            OB = __builtin_amdgcn_mfma_f32_32x32x16_bf16(af[m], bv1, OB, 0, 0, 0); \
        }                                                                      \
    } while (0)

#define COMPUTE(BUF) do {                                                      \
        bf16x8 af[4];                                                          \
        f32x16 S;                                                              \
        __builtin_amdgcn_s_setprio(1);                                         \
        QK_TILE(BUF, 0, S);                                                    \
        __builtin_amdgcn_s_setprio(0);                                         \
        SM_TILE(S, 0);                                                         \
        __builtin_amdgcn_s_setprio(1);                                         \
        QK_TILE(BUF, 1, S);                                                    \
        __builtin_amdgcn_s_setprio(0);                                         \
        SM_TILE(S, 1);                                                         \
        __builtin_amdgcn_s_setprio(1);                                         \
        PV_ALL(BUF);                                                           \
        __builtin_amdgcn_s_setprio(0);                                         \
    } while (0)

    // ---- 2-phase main loop over 32 KV tiles: stage(next); compute(cur); barrier ----
    STAGE(0);                 // tile 0 -> buf0
    __syncthreads();

#pragma unroll 1
    for (int it2 = 0; it2 < 15; ++it2) {
        STAGE(1);             // tile 2*it2+1 -> buf1 (in flight during compute)
        COMPUTE(0);           // tile 2*it2
        __syncthreads();
        STAGE(0);             // tile 2*it2+2 -> buf0
        COMPUTE(1);           // tile 2*it2+1
        __syncthreads();
    }
    STAGE(1);                 // tile 31 -> buf1
    COMPUTE(0);               // tile 30
    __syncthreads();
    COMPUTE(1);               // tile 31

#undef STAGE
#undef QK_TILE
#undef SM_TILE
#undef PV_ALL
#undef COMPUTE

    // ---- epilogue ----
    // L[q]: lane l holds the hi-half partial for q=l31; other half at lane^32.
    float Lsum = Lp0 + Lp1;
    Lsum += __shfl_xor(Lsum, 32, 64);
    const float invq = 1.0f / Lsum;               // inv for q = l31 (both hi halves)
    const int hi16 = hi << 4;                      // bpermute addr component 4*(4*hi)

#pragma unroll
    for (int r = 0; r < 16; ++r) {
        const int qb = (r & 3) + 8 * (r >> 2);     // q = qb + 4*hi
        const float invr = __builtin_bit_cast(float,
            __builtin_amdgcn_ds_bpermute((qb << 2) + hi16,
                                         __builtin_bit_cast(int, invq)));
        const int row = qrow0 + qb + 4 * hi;
        float* orow = Ob + (size_t)row * DH + l31;
        orow[0]  = OA[r] * invr;                   // d = l31
        orow[32] = OB[r] * invr;                   // d = 32 + l31
    }
}

extern "C" void kernel_launch(void* const* d_in, const int* in_sizes, int n_in,
                              void* d_out, int out_size, void* d_ws, size_t ws_size,
                              hipStream_t stream) {
    const float* Q = (const float*)d_in[0];
    const float* K = (const float*)d_in[1];
    const float* V = (const float*)d_in[2];
    float* O = (float*)d_out;

    unsigned short* Kb = (unsigned short*)d_ws;   // 16 MB bf16 K
    unsigned short* Vt = Kb + (size_t)NELEM;      // 16 MB bf16 V^T

    prep_kv<<<dim3(SEQ / 64, NBH), 256, 0, stream>>>(K, V, Kb, Vt);
    fa_fwd<<<dim3((SEQ / BM) * NBH), dim3(256), 0, stream>>>(Q, Kb, Vt, O);
}

// Round 7
// 205.869 us; speedup vs baseline: 1.7426x; 1.0007x over previous
//
#include <hip/hip_runtime.h>
#include <hip/hip_bf16.h>

#define B_   4
#define H_   16
#define SEQ  2048
#define DH   64
#define BM   128
#define BN   64
#define NBH  (B_ * H_)
#define NELEM (NBH * SEQ * DH)   // 8388608 elements per tensor

typedef __bf16 bf16x8 __attribute__((ext_vector_type(8)));
typedef float  f32x4  __attribute__((ext_vector_type(4)));
typedef float  f32x16 __attribute__((ext_vector_type(16)));
typedef unsigned short u16x8 __attribute__((ext_vector_type(8)));
typedef unsigned short u16x4 __attribute__((ext_vector_type(4)));

__device__ __forceinline__ unsigned short f2bu(float x) {
    __hip_bfloat16 h = __float2bfloat16(x);
    return __builtin_bit_cast(unsigned short, h);
}

__device__ __forceinline__ void ld_lds16(const unsigned short* g, unsigned short* l) {
    __builtin_amdgcn_global_load_lds(
        (const __attribute__((address_space(1))) unsigned int*)(g),
        (__attribute__((address_space(3))) unsigned int*)(l), 16, 0, 0);
}

// ---------- fused prepass: K fp32->bf16 (same layout) + V fp32->bf16 transposed ----------
__global__ __launch_bounds__(256)
void prep_kv(const float* __restrict__ K, const float* __restrict__ V,
             unsigned short* __restrict__ Kb, unsigned short* __restrict__ Vt) {
    __shared__ unsigned short tile[64 * 72];
    const int bh = blockIdx.y;
    const int s0 = blockIdx.x * 64;
    const int t  = threadIdx.x;

    { // K convert: 64 rows x 64 cols contiguous, 16B stores
        const float* Ki = K + (size_t)bh * SEQ * DH + (size_t)s0 * DH;
        unsigned short* Ko = Kb + (size_t)bh * SEQ * DH + (size_t)s0 * DH;
        for (int jj = 0; jj < 2; ++jj) {
            const int e = (jj * 256 + t) * 8;
            const float4 a = *reinterpret_cast<const float4*>(Ki + e);
            const float4 b = *reinterpret_cast<const float4*>(Ki + e + 4);
            u16x8 u;
            u[0] = f2bu(a.x); u[1] = f2bu(a.y); u[2] = f2bu(a.z); u[3] = f2bu(a.w);
            u[4] = f2bu(b.x); u[5] = f2bu(b.y); u[6] = f2bu(b.z); u[7] = f2bu(b.w);
            *reinterpret_cast<u16x8*>(Ko + e) = u;
        }
    }

    const float* Vb = V + (size_t)bh * SEQ * DH + (size_t)s0 * DH;
    unsigned short* Vo = Vt + (size_t)bh * DH * SEQ;
    {
        const int sl = t >> 2, d0 = (t & 3) * 16;
        for (int c = 0; c < 4; ++c) {
            const float4 v = *reinterpret_cast<const float4*>(Vb + sl * DH + d0 + c * 4);
            u16x4 u; u[0] = f2bu(v.x); u[1] = f2bu(v.y); u[2] = f2bu(v.z); u[3] = f2bu(v.w);
            *reinterpret_cast<u16x4*>(&tile[sl * 72 + d0 + c * 4]) = u;
        }
    }
    __syncthreads();
    { // transposed store: each lane 2x16B contiguous
        const int d = t >> 2, sc0 = (t & 3) * 16;
        for (int c = 0; c < 2; ++c) {
            const int s = sc0 + c * 8;
            u16x8 u;
#pragma unroll
            for (int r = 0; r < 8; ++r) u[r] = tile[(s + r) * 72 + d];
            *reinterpret_cast<u16x8*>(Vo + (size_t)d * SEQ + s0 + s) = u;
        }
    }
}

// ---------- main flash-attention kernel ----------
// R12 = R11 (32x32x16 port) + bank-conflict fix. R11 measured a DETERMINISTIC
// SQ_LDS_BANK_CONFLICT = 2^23 (R7-16x16 measured 0). Mechanism: LDS phase
// groups include stride-8 lane sets (same lane&7). Old key = row&7: in the
// 32x32 layout a stride-8 set reads rows {x,x+8,x+16,x+24} -> SAME key ->
// block index collapses to {2kt, 2kt+1} -> 4-way conflict (2-way is free,
// 4-way counts). R7's quad-geometry gave 4 distinct blocks per set -> free.
// FIX: key(r) = (r&7) ^ ((r>>3)&7) -> stride-8 set keys {k,k^1,k^2,k^3} ->
// 4 distinct blocks -> 2-way only. Contiguous octet groups unchanged
// (constant XOR within octet). Applied BOTH sides: staging gnat and read
// offsets (rows 32-63: key^4 == block-offset XOR 32 shorts).
// Everything else byte-identical to R11 (clean A/B on the swizzle key).
__global__ __launch_bounds__(256, 3)
void fa_fwd(const float* __restrict__ Qg, const unsigned short* __restrict__ Kb,
            const unsigned short* __restrict__ Vtb, float* __restrict__ Og)
{
    __shared__ __attribute__((aligned(16))) unsigned short smem[16384]; // 32 KB, 2 bufs

    const int tid  = threadIdx.x;
    const int lane = tid & 63;
    const int wave = tid >> 6;
    const int l31  = lane & 31;
    const int hi   = lane >> 5;

    // XCD-bijective swizzle: xcd = bid&7 gets bh in [8*xcd, 8*xcd+8), qtile fastest
    const int bid   = blockIdx.x;          // 0..1023
    const int xcd   = bid & 7;
    const int jj    = bid >> 3;            // 0..127
    const int bh    = (xcd << 3) | (jj >> 4);
    const int qtile = jj & 15;

    const float*          Qb  = Qg  + (size_t)bh * SEQ * DH;
    const unsigned short* Kbh = Kb  + (size_t)bh * SEQ * DH;
    const unsigned short* Vbh = Vtb + (size_t)bh * DH * SEQ;
    float*                Ob  = Og  + (size_t)bh * SEQ * DH;

    const int qrow0 = qtile * BM + wave * 32;

    const float CS = 0.125f * 1.4426950408889634f; // folded into Qf

    // Q fragments, 32x32x16 B-operand: col q = l31, k = 16*kt + 8*hi + j
    bf16x8 Qf[4];
#pragma unroll
    for (int kt = 0; kt < 4; ++kt) {
        const float* qsrc = Qb + (size_t)(qrow0 + l31) * DH + kt * 16 + hi * 8;
        const float4 a = *reinterpret_cast<const float4*>(qsrc);
        const float4 b = *reinterpret_cast<const float4*>(qsrc + 4);
        union { bf16x8 v; unsigned short u[8]; } tmp;
        tmp.u[0] = f2bu(a.x * CS); tmp.u[1] = f2bu(a.y * CS);
        tmp.u[2] = f2bu(a.z * CS); tmp.u[3] = f2bu(a.w * CS);
        tmp.u[4] = f2bu(b.x * CS); tmp.u[5] = f2bu(b.y * CS);
        tmp.u[6] = f2bu(b.z * CS); tmp.u[7] = f2bu(b.w * CS);
        Qf[kt] = tmp.v;
    }

    const f32x16 z16 = {0.f,0.f,0.f,0.f, 0.f,0.f,0.f,0.f,
                        0.f,0.f,0.f,0.f, 0.f,0.f,0.f,0.f};

    f32x16 OA = z16, OB = z16;   // O[q][d], halves d 0-31 / 32-63
    float Lp0 = 0.f, Lp1 = 0.f;  // per-lane partial row-sums (q = l31, hi half)

    // staging: global source pointers (bumped per tile) + LDS dest offsets
    const unsigned short* kp[2];
    const unsigned short* vp[2];
    int koff_st[2], voff_st[2];
    for (int i = 0; i < 2; ++i) {
        const int beta = i * 256 + tid;
        { // K: pi-permuted row (bits 2<->3 of 32-group), wide-key swizzled col block
            const int s    = beta >> 3;            // LDS row 0..63
            const int b    = beta & 7;
            const int gnat = b ^ ((s & 7) ^ ((s >> 3) & 7));   // WIDE key
            const int grow = (s & 3) + 4 * ((s >> 3) & 1) + 8 * ((s >> 2) & 1)
                           + 16 * ((s >> 4) & 1) + 32 * (s >> 5);   // pi64
            kp[i]  = Kbh + (size_t)grow * DH + gnat * 8;
        }
        { // V: natural d-row, wide-key swizzled col block
            const int d = beta >> 3;               // 0..63
            const int g = (beta & 7) ^ ((d & 7) ^ ((d >> 3) & 7));  // WIDE key
            vp[i]  = Vbh + (size_t)d * SEQ + g * 8;
        }
        koff_st[i] = (i * 256 + wave * 64) * 8;           // wave-uniform
        voff_st[i] = 4096 + (i * 256 + wave * 64) * 8;    // wave-uniform
    }

    // LDS read offsets (shorts): row = l31 (+32 via key^4 variant), block =
    // (2c+hi) ^ key. rdA for rows [0,32) (key kA), rdB for rows [32,64)
    // (key kA^4 -> block-offset XOR 32 shorts).
    const int kA = (l31 & 7) ^ ((l31 >> 3) & 7);
    int rdA[4], rdB[4];
#pragma unroll
    for (int c = 0; c < 4; ++c) {
        rdA[c] = l31 * 64 + (((((c << 1) | hi)) ^ kA) << 3);
        rdB[c] = rdA[c] ^ 32;
    }

#define STAGE(BUF) do {                                                        \
        _Pragma("unroll")                                                      \
        for (int i = 0; i < 2; ++i) {                                          \
            ld_lds16(kp[i], smem + (BUF) * 8192 + koff_st[i]);                 \
            kp[i] += BN * DH;                                                  \
        }                                                                      \
        _Pragma("unroll")                                                      \
        for (int i = 0; i < 2; ++i) {                                          \
            ld_lds16(vp[i], smem + (BUF) * 8192 + voff_st[i]);                 \
            vp[i] += BN;                                                       \
        }                                                                      \
    } while (0)

// QK C-tile T (kv rows 32T..32T+31): 4 chained MFMA over k=64; RD = rdA/rdB
#define QK_TILE(BUF, T, S, RD) do {                                            \
        _Pragma("unroll")                                                      \
        for (int kt = 0; kt < 4; ++kt) {                                       \
            const bf16x8 kf = *reinterpret_cast<const bf16x8*>(                \
                &smem[(BUF) * 8192 + (T) * 2048 + RD[kt]]);                    \
            S = __builtin_amdgcn_mfma_f32_32x32x16_bf16(kf, Qf[kt],            \
                    (kt == 0) ? z16 : S, 0, 0, 0);                             \
        }                                                                      \
    } while (0)

// softmax of C-tile T: p = exp2(S); af[2T]=p[0..7], af[2T+1]=p[8..15]; L adds
#define SM_TILE(S, T) do {                                                     \
        float p[16];                                                           \
        _Pragma("unroll")                                                      \
        for (int r = 0; r < 16; ++r) p[r] = __builtin_amdgcn_exp2f(S[r]);      \
        _Pragma("unroll")                                                      \
        for (int c1 = 0; c1 < 2; ++c1) {                                       \
            union { bf16x8 v; unsigned w[4]; } a;                              \
            _Pragma("unroll")                                                  \
            for (int w = 0; w < 4; ++w) {                                      \
                const unsigned u0 = __builtin_bit_cast(unsigned, p[8*c1 + 2*w    ]) + 0x8000u; \
                const unsigned u1 = __builtin_bit_cast(unsigned, p[8*c1 + 2*w + 1]) + 0x8000u; \
                a.w[w] = __builtin_amdgcn_perm(u1, u0, 0x07060302u);           \
            }                                                                  \
            af[2 * (T) + c1] = a.v;                                            \
        }                                                                      \
        _Pragma("unroll")                                                      \
        for (int r = 0; r < 8; ++r)  Lp0 += p[r];                              \
        _Pragma("unroll")                                                      \
        for (int r = 8; r < 16; ++r) Lp1 += p[r];                              \
    } while (0)

// PV: A = af[m] (P frags, kv=16m+8hi+j), B = V^T LDS; both O halves interleaved
#define PV_ALL(BUF) do {                                                       \
        _Pragma("unroll")                                                      \
        for (int m = 0; m < 4; ++m) {                                          \
            const bf16x8 bv0 = *reinterpret_cast<const bf16x8*>(               \
                &smem[(BUF) * 8192 + 4096 + rdA[m]]);                          \
            const bf16x8 bv1 = *reinterpret_cast<const bf16x8*>(               \
                &smem[(BUF) * 8192 + 4096 + 2048 + rdB[m]]);                   \
            OA = __builtin_amdgcn_mfma_f32_32x32x16_bf16(af[m], bv0, OA, 0, 0, 0); \
            OB = __builtin_amdgcn_mfma_f32_32x32x16_bf16(af[m], bv1, OB, 0, 0, 0); \
        }                                                                      \
    } while (0)

#define COMPUTE(BUF) do {                                                      \
        bf16x8 af[4];                                                          \
        f32x16 S;                                                              \
        __builtin_amdgcn_s_setprio(1);                                         \
        QK_TILE(BUF, 0, S, rdA);                                               \
        __builtin_amdgcn_s_setprio(0);                                         \
        SM_TILE(S, 0);                                                         \
        __builtin_amdgcn_s_setprio(1);                                         \
        QK_TILE(BUF, 1, S, rdB);                                               \
        __builtin_amdgcn_s_setprio(0);                                         \
        SM_TILE(S, 1);                                                         \
        __builtin_amdgcn_s_setprio(1);                                         \
        PV_ALL(BUF);                                                           \
        __builtin_amdgcn_s_setprio(0);                                         \
    } while (0)

    // ---- 2-phase main loop over 32 KV tiles: stage(next); compute(cur); barrier ----
    STAGE(0);                 // tile 0 -> buf0
    __syncthreads();

#pragma unroll 1
    for (int it2 = 0; it2 < 15; ++it2) {
        STAGE(1);             // tile 2*it2+1 -> buf1 (in flight during compute)
        COMPUTE(0);           // tile 2*it2
        __syncthreads();
        STAGE(0);             // tile 2*it2+2 -> buf0
        COMPUTE(1);           // tile 2*it2+1
        __syncthreads();
    }
    STAGE(1);                 // tile 31 -> buf1
    COMPUTE(0);               // tile 30
    __syncthreads();
    COMPUTE(1);               // tile 31

#undef STAGE
#undef QK_TILE
#undef SM_TILE
#undef PV_ALL
#undef COMPUTE

    // ---- epilogue ----
    // L[q]: lane l holds the hi-half partial for q=l31; other half at lane^32.
    float Lsum = Lp0 + Lp1;
    Lsum += __shfl_xor(Lsum, 32, 64);
    const float invq = 1.0f / Lsum;               // inv for q = l31 (both hi halves)
    const int hi16 = hi << 4;                      // bpermute addr component 4*(4*hi)

#pragma unroll
    for (int r = 0; r < 16; ++r) {
        const int qb = (r & 3) + 8 * (r >> 2);     // q = qb + 4*hi
        const float invr = __builtin_bit_cast(float,
            __builtin_amdgcn_ds_bpermute((qb << 2) + hi16,
                                         __builtin_bit_cast(int, invq)));
        const int row = qrow0 + qb + 4 * hi;
        float* orow = Ob + (size_t)row * DH + l31;
        orow[0]  = OA[r] * invr;                   // d = l31
        orow[32] = OB[r] * invr;                   // d = 32 + l31
    }
}

extern "C" void kernel_launch(void* const* d_in, const int* in_sizes, int n_in,
                              void* d_out, int out_size, void* d_ws, size_t ws_size,
                              hipStream_t stream) {
    const float* Q = (const float*)d_in[0];
    const float* K = (const float*)d_in[1];
    const float* V = (const float*)d_in[2];
    float* O = (float*)d_out;

    unsigned short* Kb = (unsigned short*)d_ws;   // 16 MB bf16 K
    unsigned short* Vt = Kb + (size_t)NELEM;      // 16 MB bf16 V^T

    prep_kv<<<dim3(SEQ / 64, NBH), 256, 0, stream>>>(K, V, Kb, Vt);
    fa_fwd<<<dim3((SEQ / BM) * NBH), dim3(256), 0, stream>>>(Q, Kb, Vt, O);
}

// Round 8
// 204.866 us; speedup vs baseline: 1.7511x; 1.0049x over previous
//
#include <hip/hip_runtime.h>
#include <hip/hip_bf16.h>

#define B_   4
#define H_   16
#define SEQ  2048
#define DH   64
#define BM   128
#define BN   64
#define NBH  (B_ * H_)
#define NELEM (NBH * SEQ * DH)   // 8388608 elements per tensor

typedef __bf16 bf16x8 __attribute__((ext_vector_type(8)));
typedef float  f32x4  __attribute__((ext_vector_type(4)));
typedef float  f32x16 __attribute__((ext_vector_type(16)));
typedef unsigned short u16x8 __attribute__((ext_vector_type(8)));
typedef unsigned short u16x4 __attribute__((ext_vector_type(4)));

__device__ __forceinline__ unsigned short f2bu(float x) {
    __hip_bfloat16 h = __float2bfloat16(x);
    return __builtin_bit_cast(unsigned short, h);
}

__device__ __forceinline__ void ld_lds16(const unsigned short* g, unsigned short* l) {
    __builtin_amdgcn_global_load_lds(
        (const __attribute__((address_space(1))) unsigned int*)(g),
        (__attribute__((address_space(3))) unsigned int*)(l), 16, 0, 0);
}

// ---------- fused prepass: K fp32->bf16 (same layout) + V fp32->bf16 transposed ----------
__global__ __launch_bounds__(256)
void prep_kv(const float* __restrict__ K, const float* __restrict__ V,
             unsigned short* __restrict__ Kb, unsigned short* __restrict__ Vt) {
    __shared__ unsigned short tile[64 * 72];
    const int bh = blockIdx.y;
    const int s0 = blockIdx.x * 64;
    const int t  = threadIdx.x;

    { // K convert: 64 rows x 64 cols contiguous, 16B stores
        const float* Ki = K + (size_t)bh * SEQ * DH + (size_t)s0 * DH;
        unsigned short* Ko = Kb + (size_t)bh * SEQ * DH + (size_t)s0 * DH;
        for (int jj = 0; jj < 2; ++jj) {
            const int e = (jj * 256 + t) * 8;
            const float4 a = *reinterpret_cast<const float4*>(Ki + e);
            const float4 b = *reinterpret_cast<const float4*>(Ki + e + 4);
            u16x8 u;
            u[0] = f2bu(a.x); u[1] = f2bu(a.y); u[2] = f2bu(a.z); u[3] = f2bu(a.w);
            u[4] = f2bu(b.x); u[5] = f2bu(b.y); u[6] = f2bu(b.z); u[7] = f2bu(b.w);
            *reinterpret_cast<u16x8*>(Ko + e) = u;
        }
    }

    const float* Vb = V + (size_t)bh * SEQ * DH + (size_t)s0 * DH;
    unsigned short* Vo = Vt + (size_t)bh * DH * SEQ;
    {
        const int sl = t >> 2, d0 = (t & 3) * 16;
        for (int c = 0; c < 4; ++c) {
            const float4 v = *reinterpret_cast<const float4*>(Vb + sl * DH + d0 + c * 4);
            u16x4 u; u[0] = f2bu(v.x); u[1] = f2bu(v.y); u[2] = f2bu(v.z); u[3] = f2bu(v.w);
            *reinterpret_cast<u16x4*>(&tile[sl * 72 + d0 + c * 4]) = u;
        }
    }
    __syncthreads();
    { // transposed store: each lane 2x16B contiguous
        const int d = t >> 2, sc0 = (t & 3) * 16;
        for (int c = 0; c < 2; ++c) {
            const int s = sc0 + c * 8;
            u16x8 u;
#pragma unroll
            for (int r = 0; r < 8; ++r) u[r] = tile[(s + r) * 72 + d];
            *reinterpret_cast<u16x8*>(Vo + (size_t)d * SEQ + s0 + s) = u;
        }
    }
}

// ---------- main flash-attention kernel ----------
// R13 = R12 (32x32x16, conflict-free wide-key swizzle) + cross-half software
// pipeline. R12 post-mortem: conflicts 8.4M->0 but plateau ~90us persists
// across every structure variant; the common factor is the intra-tile chain
// QK -> SM(dep) -> PV(dep) that the compiler cannot reorder. Fix: stream the
// 64 C-tiles (2 per KV tile) with a 1-deep pipeline so each step executes
//   QK(c+1)  [MFMA, independent]  ||  SM(c) [VALU, operands long-ready]
//   -> PV(c) [MFMA]
// The scheduler slots SM's exp2/pack into QK's MFMA shadow; the matrix pipe
// sees QK,PV,QK,PV back-to-back. Requires V(i) alive while QK(i+1) runs ->
// THREE LDS buffers (48KB), loop unrolled by 3 for compile-time buf indices.
// Extra live state: one more f32x16 + af2 => ~130 VGPR, cap 168 (256,3).
// Staging/swizzles/epilogue byte-identical to R12. setprio dropped (neutral
// R6-R12; would pin the boundaries we want blended).
__global__ __launch_bounds__(256, 3)
void fa_fwd(const float* __restrict__ Qg, const unsigned short* __restrict__ Kb,
            const unsigned short* __restrict__ Vtb, float* __restrict__ Og)
{
    __shared__ __attribute__((aligned(16))) unsigned short smem[24576]; // 48 KB, 3 bufs

    const int tid  = threadIdx.x;
    const int lane = tid & 63;
    const int wave = tid >> 6;
    const int l31  = lane & 31;
    const int hi   = lane >> 5;

    // XCD-bijective swizzle: xcd = bid&7 gets bh in [8*xcd, 8*xcd+8), qtile fastest
    const int bid   = blockIdx.x;          // 0..1023
    const int xcd   = bid & 7;
    const int jj    = bid >> 3;            // 0..127
    const int bh    = (xcd << 3) | (jj >> 4);
    const int qtile = jj & 15;

    const float*          Qb  = Qg  + (size_t)bh * SEQ * DH;
    const unsigned short* Kbh = Kb  + (size_t)bh * SEQ * DH;
    const unsigned short* Vbh = Vtb + (size_t)bh * DH * SEQ;
    float*                Ob  = Og  + (size_t)bh * SEQ * DH;

    const int qrow0 = qtile * BM + wave * 32;

    const float CS = 0.125f * 1.4426950408889634f; // folded into Qf

    // Q fragments, 32x32x16 B-operand: col q = l31, k = 16*kt + 8*hi + j
    bf16x8 Qf[4];
#pragma unroll
    for (int kt = 0; kt < 4; ++kt) {
        const float* qsrc = Qb + (size_t)(qrow0 + l31) * DH + kt * 16 + hi * 8;
        const float4 a = *reinterpret_cast<const float4*>(qsrc);
        const float4 b = *reinterpret_cast<const float4*>(qsrc + 4);
        union { bf16x8 v; unsigned short u[8]; } tmp;
        tmp.u[0] = f2bu(a.x * CS); tmp.u[1] = f2bu(a.y * CS);
        tmp.u[2] = f2bu(a.z * CS); tmp.u[3] = f2bu(a.w * CS);
        tmp.u[4] = f2bu(b.x * CS); tmp.u[5] = f2bu(b.y * CS);
        tmp.u[6] = f2bu(b.z * CS); tmp.u[7] = f2bu(b.w * CS);
        Qf[kt] = tmp.v;
    }

    const f32x16 z16 = {0.f,0.f,0.f,0.f, 0.f,0.f,0.f,0.f,
                        0.f,0.f,0.f,0.f, 0.f,0.f,0.f,0.f};

    f32x16 OA = z16, OB = z16;   // O[q][d], halves d 0-31 / 32-63
    float Lp0 = 0.f, Lp1 = 0.f;  // per-lane partial row-sums (q = l31, hi half)

    // staging: global source pointers (bumped per tile) + LDS dest offsets
    const unsigned short* kp[2];
    const unsigned short* vp[2];
    int koff_st[2], voff_st[2];
    for (int i = 0; i < 2; ++i) {
        const int beta = i * 256 + tid;
        { // K: pi-permuted row (bits 2<->3 of 32-group), wide-key swizzled col block
            const int s    = beta >> 3;            // LDS row 0..63
            const int b    = beta & 7;
            const int gnat = b ^ ((s & 7) ^ ((s >> 3) & 7));   // WIDE key
            const int grow = (s & 3) + 4 * ((s >> 3) & 1) + 8 * ((s >> 2) & 1)
                           + 16 * ((s >> 4) & 1) + 32 * (s >> 5);   // pi64
            kp[i]  = Kbh + (size_t)grow * DH + gnat * 8;
        }
        { // V: natural d-row, wide-key swizzled col block
            const int d = beta >> 3;               // 0..63
            const int g = (beta & 7) ^ ((d & 7) ^ ((d >> 3) & 7));  // WIDE key
            vp[i]  = Vbh + (size_t)d * SEQ + g * 8;
        }
        koff_st[i] = (i * 256 + wave * 64) * 8;           // wave-uniform
        voff_st[i] = 4096 + (i * 256 + wave * 64) * 8;    // wave-uniform
    }

    // LDS read offsets (shorts): row = l31, block = (2c+hi) ^ key.
    // rdA rows [0,32) (key kA), rdB rows [32,64) (key kA^4 == XOR 32 shorts).
    const int kA = (l31 & 7) ^ ((l31 >> 3) & 7);
    int rdA[4], rdB[4];
#pragma unroll
    for (int c = 0; c < 4; ++c) {
        rdA[c] = l31 * 64 + (((((c << 1) | hi)) ^ kA) << 3);
        rdB[c] = rdA[c] ^ 32;
    }

#define STAGE(BUF) do {                                                        \
        _Pragma("unroll")                                                      \
        for (int i = 0; i < 2; ++i) {                                          \
            ld_lds16(kp[i], smem + (BUF) * 8192 + koff_st[i]);                 \
            kp[i] += BN * DH;                                                  \
        }                                                                      \
        _Pragma("unroll")                                                      \
        for (int i = 0; i < 2; ++i) {                                          \
            ld_lds16(vp[i], smem + (BUF) * 8192 + voff_st[i]);                 \
            vp[i] += BN;                                                       \
        }                                                                      \
    } while (0)

// QK C-tile T of the tile in BUF (kv rows 32T..32T+31): 4 chained MFMA, k=64
#define QK_TILE(BUF, T, S, RD) do {                                            \
        _Pragma("unroll")                                                      \
        for (int kt = 0; kt < 4; ++kt) {                                       \
            const bf16x8 kf = *reinterpret_cast<const bf16x8*>(                \
                &smem[(BUF) * 8192 + (T) * 2048 + RD[kt]]);                    \
            S = __builtin_amdgcn_mfma_f32_32x32x16_bf16(kf, Qf[kt],            \
                    (kt == 0) ? z16 : S, 0, 0, 0);                             \
        }                                                                      \
    } while (0)

// softmax of one C-tile: p = exp2(S); AF[0]=p[0..7], AF[1]=p[8..15]; L adds
#define SM_C(S, AF) do {                                                       \
        float p[16];                                                           \
        _Pragma("unroll")                                                      \
        for (int r = 0; r < 16; ++r) p[r] = __builtin_amdgcn_exp2f(S[r]);      \
        _Pragma("unroll")                                                      \
        for (int c1 = 0; c1 < 2; ++c1) {                                       \
            union { bf16x8 v; unsigned w[4]; } a;                              \
            _Pragma("unroll")                                                  \
            for (int w = 0; w < 4; ++w) {                                      \
                const unsigned u0 = __builtin_bit_cast(unsigned, p[8*c1 + 2*w    ]) + 0x8000u; \
                const unsigned u1 = __builtin_bit_cast(unsigned, p[8*c1 + 2*w + 1]) + 0x8000u; \
                a.w[w] = __builtin_amdgcn_perm(u1, u0, 0x07060302u);           \
            }                                                                  \
            AF[c1] = a.v;                                                      \
        }                                                                      \
        _Pragma("unroll")                                                      \
        for (int r = 0; r < 8; ++r)  Lp0 += p[r];                              \
        _Pragma("unroll")                                                      \
        for (int r = 8; r < 16; ++r) Lp1 += p[r];                              \
    } while (0)

// PV of C-half T (kv rows 32T..32T+31): A = AF[mm] (m = 2T+mm), B = V^T LDS
#define PV_HALF(BUF, T, AF) do {                                               \
        _Pragma("unroll")                                                      \
        for (int mm = 0; mm < 2; ++mm) {                                       \
            const int m = 2 * (T) + mm;                                        \
            const bf16x8 bv0 = *reinterpret_cast<const bf16x8*>(               \
                &smem[(BUF) * 8192 + 4096 + rdA[m]]);                          \
            const bf16x8 bv1 = *reinterpret_cast<const bf16x8*>(               \
                &smem[(BUF) * 8192 + 4096 + 2048 + rdB[m]]);                   \
            OA = __builtin_amdgcn_mfma_f32_32x32x16_bf16(AF[mm], bv0, OA, 0, 0, 0); \
            OB = __builtin_amdgcn_mfma_f32_32x32x16_bf16(AF[mm], bv1, OB, 0, 0, 0); \
        }                                                                      \
    } while (0)

// one KV-tile step of the pipeline. Entering: SA = unprocessed QK of
// (tile @ B0, half0). B1 = next tile's buffer, B2 = staging target (tile+2).
#define STEP(B0, B1, B2) do {                                                  \
        STAGE(B2);                                                             \
        QK_TILE(B0, 1, SB, rdB);           /* h1 of current tile (indep) */    \
        { bf16x8 af2[2]; SM_C(SA, af2); PV_HALF(B0, 0, af2); }  /* finish h0 */\
        QK_TILE(B1, 0, SA, rdA);           /* h0 of next tile (indep) */       \
        { bf16x8 af2[2]; SM_C(SB, af2); PV_HALF(B0, 1, af2); }  /* finish h1 */\
        __syncthreads();                                                       \
    } while (0)

    f32x16 SA, SB;

    // ---- prologue: stage tiles 0,1; QK of (tile0, half0) ----
    STAGE(0);
    __syncthreads();
    STAGE(1);                       // tile 1 in flight under first QK
    QK_TILE(0, 0, SA, rdA);         // c = 0
    __syncthreads();                // tile 1 landed

    // ---- main loop: 30 KV-tile steps, buffers rotate 0,1,2 ----
#pragma unroll 1
    for (int it3 = 0; it3 < 10; ++it3) {
        STEP(0, 1, 2);
        STEP(1, 2, 0);
        STEP(2, 0, 1);
    }

    // ---- tail: tiles 30 (@buf0) and 31 (@buf1), no more staging ----
    QK_TILE(0, 1, SB, rdB);
    { bf16x8 af2[2]; SM_C(SA, af2); PV_HALF(0, 0, af2); }
    QK_TILE(1, 0, SA, rdA);
    { bf16x8 af2[2]; SM_C(SB, af2); PV_HALF(0, 1, af2); }
    QK_TILE(1, 1, SB, rdB);
    { bf16x8 af2[2]; SM_C(SA, af2); PV_HALF(1, 0, af2); }
    { bf16x8 af2[2]; SM_C(SB, af2); PV_HALF(1, 1, af2); }

#undef STAGE
#undef QK_TILE
#undef SM_C
#undef PV_HALF
#undef STEP

    // ---- epilogue ----
    // L[q]: lane l holds the hi-half partial for q=l31; other half at lane^32.
    float Lsum = Lp0 + Lp1;
    Lsum += __shfl_xor(Lsum, 32, 64);
    const float invq = 1.0f / Lsum;               // inv for q = l31 (both hi halves)
    const int hi16 = hi << 4;                      // bpermute addr component 4*(4*hi)

#pragma unroll
    for (int r = 0; r < 16; ++r) {
        const int qb = (r & 3) + 8 * (r >> 2);     // q = qb + 4*hi
        const float invr = __builtin_bit_cast(float,
            __builtin_amdgcn_ds_bpermute((qb << 2) + hi16,
                                         __builtin_bit_cast(int, invq)));
        const int row = qrow0 + qb + 4 * hi;
        float* orow = Ob + (size_t)row * DH + l31;
        orow[0]  = OA[r] * invr;                   // d = l31
        orow[32] = OB[r] * invr;                   // d = 32 + l31
    }
}

extern "C" void kernel_launch(void* const* d_in, const int* in_sizes, int n_in,
                              void* d_out, int out_size, void* d_ws, size_t ws_size,
                              hipStream_t stream) {
    const float* Q = (const float*)d_in[0];
    const float* K = (const float*)d_in[1];
    const float* V = (const float*)d_in[2];
    float* O = (float*)d_out;

    unsigned short* Kb = (unsigned short*)d_ws;   // 16 MB bf16 K
    unsigned short* Vt = Kb + (size_t)NELEM;      // 16 MB bf16 V^T

    prep_kv<<<dim3(SEQ / 64, NBH), 256, 0, stream>>>(K, V, Kb, Vt);
    fa_fwd<<<dim3((SEQ / BM) * NBH), dim3(256), 0, stream>>>(Q, Kb, Vt, O);
}

// Round 9
// 200.525 us; speedup vs baseline: 1.7890x; 1.0216x over previous
//
#include <hip/hip_runtime.h>
#include <hip/hip_bf16.h>

#define B_   4
#define H_   16
#define SEQ  2048
#define DH   64
#define BM   128
#define BN   64
#define NBH  (B_ * H_)
#define NELEM (NBH * SEQ * DH)   // 8388608 elements per tensor

typedef __bf16 bf16x8 __attribute__((ext_vector_type(8)));
typedef float  f32x4  __attribute__((ext_vector_type(4)));
typedef float  f32x16 __attribute__((ext_vector_type(16)));
typedef unsigned short u16x8 __attribute__((ext_vector_type(8)));
typedef unsigned short u16x4 __attribute__((ext_vector_type(4)));

__device__ __forceinline__ unsigned short f2bu(float x) {
    __hip_bfloat16 h = __float2bfloat16(x);
    return __builtin_bit_cast(unsigned short, h);
}

__device__ __forceinline__ void ld_lds16(const unsigned short* g, unsigned short* l) {
    __builtin_amdgcn_global_load_lds(
        (const __attribute__((address_space(1))) unsigned int*)(g),
        (__attribute__((address_space(3))) unsigned int*)(l), 16, 0, 0);
}

// ---------- fused prepass v2: K fp32->bf16 (streaming) + V fp32->bf16 transposed ----------
// R14 rewrite. Old version's V path: strided global reads (4x16B per 256B row
// window per instr), 16 scalar LDS reads/thread on an 8-way-conflicted
// mapping (16-row stride x 36 words == 0 mod 32), and 32B-holed V^T stores.
// New: V reads float8-contiguous (wave = 2KB coalesced, same as K), LDS
// write b128 linear, transposed read-out lane o -> (d=o>>3, sblk=(o&7)*8)
// so each 8-lane group writes 128B contiguous of one V^T row.
__global__ __launch_bounds__(256)
void prep_kv(const float* __restrict__ K, const float* __restrict__ V,
             unsigned short* __restrict__ Kb, unsigned short* __restrict__ Vt) {
    __shared__ unsigned short tile[64 * 64];   // 8 KB bf16 [s][d]
    const int bh = blockIdx.y;
    const int s0 = blockIdx.x * 64;
    const int t  = threadIdx.x;

    { // K convert: 64x64 = 4096 floats; 2 iters x 256 thr x float8, coalesced
        const float* Ki = K + (size_t)bh * SEQ * DH + (size_t)s0 * DH;
        unsigned short* Ko = Kb + (size_t)bh * SEQ * DH + (size_t)s0 * DH;
#pragma unroll
        for (int i = 0; i < 2; ++i) {
            const int e = (i * 256 + t) * 8;
            const float4 a = *reinterpret_cast<const float4*>(Ki + e);
            const float4 b = *reinterpret_cast<const float4*>(Ki + e + 4);
            u16x8 u;
            u[0] = f2bu(a.x); u[1] = f2bu(a.y); u[2] = f2bu(a.z); u[3] = f2bu(a.w);
            u[4] = f2bu(b.x); u[5] = f2bu(b.y); u[6] = f2bu(b.z); u[7] = f2bu(b.w);
            *reinterpret_cast<u16x8*>(Ko + e) = u;
        }
    }

    { // V stage: float8 contiguous reads -> bf16 -> LDS linear (b128 writes)
        const float* Vb = V + (size_t)bh * SEQ * DH + (size_t)s0 * DH;
#pragma unroll
        for (int i = 0; i < 2; ++i) {
            const int e = (i * 256 + t) * 8;    // == s*64 + d8, linear
            const float4 a = *reinterpret_cast<const float4*>(Vb + e);
            const float4 b = *reinterpret_cast<const float4*>(Vb + e + 4);
            u16x8 u;
            u[0] = f2bu(a.x); u[1] = f2bu(a.y); u[2] = f2bu(a.z); u[3] = f2bu(a.w);
            u[4] = f2bu(b.x); u[5] = f2bu(b.y); u[6] = f2bu(b.z); u[7] = f2bu(b.w);
            *reinterpret_cast<u16x8*>(&tile[e]) = u;
        }
    }
    __syncthreads();
    { // transposed write-out: o -> d = o>>3, sblk = (o&7)*8; 8-lane group
      // writes 128B contiguous of row d. LDS reads: paired lanes share the
      // exact word (broadcast); worst case ~8-way on the rest - ~2us chip.
        unsigned short* Vo = Vt + (size_t)bh * DH * SEQ;
#pragma unroll
        for (int i = 0; i < 2; ++i) {
            const int o = i * 256 + t;
            const int d = o >> 3, sb = (o & 7) * 8;
            u16x8 u;
#pragma unroll
            for (int r = 0; r < 8; ++r) u[r] = tile[(sb + r) * 64 + d];
            *reinterpret_cast<u16x8*>(Vo + (size_t)d * SEQ + s0 + sb) = u;
        }
    }
}

// ---------- main flash-attention kernel ----------
// R14: byte-identical to R13 (best measured, 88.5us) - this round's single
// variable is prep_kv. R13 = 32x32x16 + wide-key conflict-free swizzle +
// cross-half software pipeline (QK(c+1) || SM(c) -> PV(c)), 3 LDS buffers.
__global__ __launch_bounds__(256, 3)
void fa_fwd(const float* __restrict__ Qg, const unsigned short* __restrict__ Kb,
            const unsigned short* __restrict__ Vtb, float* __restrict__ Og)
{
    __shared__ __attribute__((aligned(16))) unsigned short smem[24576]; // 48 KB, 3 bufs

    const int tid  = threadIdx.x;
    const int lane = tid & 63;
    const int wave = tid >> 6;
    const int l31  = lane & 31;
    const int hi   = lane >> 5;

    // XCD-bijective swizzle: xcd = bid&7 gets bh in [8*xcd, 8*xcd+8), qtile fastest
    const int bid   = blockIdx.x;          // 0..1023
    const int xcd   = bid & 7;
    const int jj    = bid >> 3;            // 0..127
    const int bh    = (xcd << 3) | (jj >> 4);
    const int qtile = jj & 15;

    const float*          Qb  = Qg  + (size_t)bh * SEQ * DH;
    const unsigned short* Kbh = Kb  + (size_t)bh * SEQ * DH;
    const unsigned short* Vbh = Vtb + (size_t)bh * DH * SEQ;
    float*                Ob  = Og  + (size_t)bh * SEQ * DH;

    const int qrow0 = qtile * BM + wave * 32;

    const float CS = 0.125f * 1.4426950408889634f; // folded into Qf

    // Q fragments, 32x32x16 B-operand: col q = l31, k = 16*kt + 8*hi + j
    bf16x8 Qf[4];
#pragma unroll
    for (int kt = 0; kt < 4; ++kt) {
        const float* qsrc = Qb + (size_t)(qrow0 + l31) * DH + kt * 16 + hi * 8;
        const float4 a = *reinterpret_cast<const float4*>(qsrc);
        const float4 b = *reinterpret_cast<const float4*>(qsrc + 4);
        union { bf16x8 v; unsigned short u[8]; } tmp;
        tmp.u[0] = f2bu(a.x * CS); tmp.u[1] = f2bu(a.y * CS);
        tmp.u[2] = f2bu(a.z * CS); tmp.u[3] = f2bu(a.w * CS);
        tmp.u[4] = f2bu(b.x * CS); tmp.u[5] = f2bu(b.y * CS);
        tmp.u[6] = f2bu(b.z * CS); tmp.u[7] = f2bu(b.w * CS);
        Qf[kt] = tmp.v;
    }

    const f32x16 z16 = {0.f,0.f,0.f,0.f, 0.f,0.f,0.f,0.f,
                        0.f,0.f,0.f,0.f, 0.f,0.f,0.f,0.f};

    f32x16 OA = z16, OB = z16;   // O[q][d], halves d 0-31 / 32-63
    float Lp0 = 0.f, Lp1 = 0.f;  // per-lane partial row-sums (q = l31, hi half)

    // staging: global source pointers (bumped per tile) + LDS dest offsets
    const unsigned short* kp[2];
    const unsigned short* vp[2];
    int koff_st[2], voff_st[2];
    for (int i = 0; i < 2; ++i) {
        const int beta = i * 256 + tid;
        { // K: pi-permuted row (bits 2<->3 of 32-group), wide-key swizzled col block
            const int s    = beta >> 3;            // LDS row 0..63
            const int b    = beta & 7;
            const int gnat = b ^ ((s & 7) ^ ((s >> 3) & 7));   // WIDE key
            const int grow = (s & 3) + 4 * ((s >> 3) & 1) + 8 * ((s >> 2) & 1)
                           + 16 * ((s >> 4) & 1) + 32 * (s >> 5);   // pi64
            kp[i]  = Kbh + (size_t)grow * DH + gnat * 8;
        }
        { // V: natural d-row, wide-key swizzled col block
            const int d = beta >> 3;               // 0..63
            const int g = (beta & 7) ^ ((d & 7) ^ ((d >> 3) & 7));  // WIDE key
            vp[i]  = Vbh + (size_t)d * SEQ + g * 8;
        }
        koff_st[i] = (i * 256 + wave * 64) * 8;           // wave-uniform
        voff_st[i] = 4096 + (i * 256 + wave * 64) * 8;    // wave-uniform
    }

    // LDS read offsets (shorts): row = l31, block = (2c+hi) ^ key.
    // rdA rows [0,32) (key kA), rdB rows [32,64) (key kA^4 == XOR 32 shorts).
    const int kA = (l31 & 7) ^ ((l31 >> 3) & 7);
    int rdA[4], rdB[4];
#pragma unroll
    for (int c = 0; c < 4; ++c) {
        rdA[c] = l31 * 64 + (((((c << 1) | hi)) ^ kA) << 3);
        rdB[c] = rdA[c] ^ 32;
    }

#define STAGE(BUF) do {                                                        \
        _Pragma("unroll")                                                      \
        for (int i = 0; i < 2; ++i) {                                          \
            ld_lds16(kp[i], smem + (BUF) * 8192 + koff_st[i]);                 \
            kp[i] += BN * DH;                                                  \
        }                                                                      \
        _Pragma("unroll")                                                      \
        for (int i = 0; i < 2; ++i) {                                          \
            ld_lds16(vp[i], smem + (BUF) * 8192 + voff_st[i]);                 \
            vp[i] += BN;                                                       \
        }                                                                      \
    } while (0)

// QK C-tile T of the tile in BUF (kv rows 32T..32T+31): 4 chained MFMA, k=64
#define QK_TILE(BUF, T, S, RD) do {                                            \
        _Pragma("unroll")                                                      \
        for (int kt = 0; kt < 4; ++kt) {                                       \
            const bf16x8 kf = *reinterpret_cast<const bf16x8*>(                \
                &smem[(BUF) * 8192 + (T) * 2048 + RD[kt]]);                    \
            S = __builtin_amdgcn_mfma_f32_32x32x16_bf16(kf, Qf[kt],            \
                    (kt == 0) ? z16 : S, 0, 0, 0);                             \
        }                                                                      \
    } while (0)

// softmax of one C-tile: p = exp2(S); AF[0]=p[0..7], AF[1]=p[8..15]; L adds
#define SM_C(S, AF) do {                                                       \
        float p[16];                                                           \
        _Pragma("unroll")                                                      \
        for (int r = 0; r < 16; ++r) p[r] = __builtin_amdgcn_exp2f(S[r]);      \
        _Pragma("unroll")                                                      \
        for (int c1 = 0; c1 < 2; ++c1) {                                       \
            union { bf16x8 v; unsigned w[4]; } a;                              \
            _Pragma("unroll")                                                  \
            for (int w = 0; w < 4; ++w) {                                      \
                const unsigned u0 = __builtin_bit_cast(unsigned, p[8*c1 + 2*w    ]) + 0x8000u; \
                const unsigned u1 = __builtin_bit_cast(unsigned, p[8*c1 + 2*w + 1]) + 0x8000u; \
                a.w[w] = __builtin_amdgcn_perm(u1, u0, 0x07060302u);           \
            }                                                                  \
            AF[c1] = a.v;                                                      \
        }                                                                      \
        _Pragma("unroll")                                                      \
        for (int r = 0; r < 8; ++r)  Lp0 += p[r];                              \
        _Pragma("unroll")                                                      \
        for (int r = 8; r < 16; ++r) Lp1 += p[r];                              \
    } while (0)

// PV of C-half T (kv rows 32T..32T+31): A = AF[mm] (m = 2T+mm), B = V^T LDS
#define PV_HALF(BUF, T, AF) do {                                               \
        _Pragma("unroll")                                                      \
        for (int mm = 0; mm < 2; ++mm) {                                       \
            const int m = 2 * (T) + mm;                                        \
            const bf16x8 bv0 = *reinterpret_cast<const bf16x8*>(               \
                &smem[(BUF) * 8192 + 4096 + rdA[m]]);                          \
            const bf16x8 bv1 = *reinterpret_cast<const bf16x8*>(               \
                &smem[(BUF) * 8192 + 4096 + 2048 + rdB[m]]);                   \
            OA = __builtin_amdgcn_mfma_f32_32x32x16_bf16(AF[mm], bv0, OA, 0, 0, 0); \
            OB = __builtin_amdgcn_mfma_f32_32x32x16_bf16(AF[mm], bv1, OB, 0, 0, 0); \
        }                                                                      \
    } while (0)

// one KV-tile step of the pipeline. Entering: SA = unprocessed QK of
// (tile @ B0, half0). B1 = next tile's buffer, B2 = staging target (tile+2).
#define STEP(B0, B1, B2) do {                                                  \
        STAGE(B2);                                                             \
        QK_TILE(B0, 1, SB, rdB);           /* h1 of current tile (indep) */    \
        { bf16x8 af2[2]; SM_C(SA, af2); PV_HALF(B0, 0, af2); }  /* finish h0 */\
        QK_TILE(B1, 0, SA, rdA);           /* h0 of next tile (indep) */       \
        { bf16x8 af2[2]; SM_C(SB, af2); PV_HALF(B0, 1, af2); }  /* finish h1 */\
        __syncthreads();                                                       \
    } while (0)

    f32x16 SA, SB;

    // ---- prologue: stage tiles 0,1; QK of (tile0, half0) ----
    STAGE(0);
    __syncthreads();
    STAGE(1);                       // tile 1 in flight under first QK
    QK_TILE(0, 0, SA, rdA);         // c = 0
    __syncthreads();                // tile 1 landed

    // ---- main loop: 30 KV-tile steps, buffers rotate 0,1,2 ----
#pragma unroll 1
    for (int it3 = 0; it3 < 10; ++it3) {
        STEP(0, 1, 2);
        STEP(1, 2, 0);
        STEP(2, 0, 1);
    }

    // ---- tail: tiles 30 (@buf0) and 31 (@buf1), no more staging ----
    QK_TILE(0, 1, SB, rdB);
    { bf16x8 af2[2]; SM_C(SA, af2); PV_HALF(0, 0, af2); }
    QK_TILE(1, 0, SA, rdA);
    { bf16x8 af2[2]; SM_C(SB, af2); PV_HALF(0, 1, af2); }
    QK_TILE(1, 1, SB, rdB);
    { bf16x8 af2[2]; SM_C(SA, af2); PV_HALF(1, 0, af2); }
    { bf16x8 af2[2]; SM_C(SB, af2); PV_HALF(1, 1, af2); }

#undef STAGE
#undef QK_TILE
#undef SM_C
#undef PV_HALF
#undef STEP

    // ---- epilogue ----
    // L[q]: lane l holds the hi-half partial for q=l31; other half at lane^32.
    float Lsum = Lp0 + Lp1;
    Lsum += __shfl_xor(Lsum, 32, 64);
    const float invq = 1.0f / Lsum;               // inv for q = l31 (both hi halves)
    const int hi16 = hi << 4;                      // bpermute addr component 4*(4*hi)

#pragma unroll
    for (int r = 0; r < 16; ++r) {
        const int qb = (r & 3) + 8 * (r >> 2);     // q = qb + 4*hi
        const float invr = __builtin_bit_cast(float,
            __builtin_amdgcn_ds_bpermute((qb << 2) + hi16,
                                         __builtin_bit_cast(int, invq)));
        const int row = qrow0 + qb + 4 * hi;
        float* orow = Ob + (size_t)row * DH + l31;
        orow[0]  = OA[r] * invr;                   // d = l31
        orow[32] = OB[r] * invr;                   // d = 32 + l31
    }
}

extern "C" void kernel_launch(void* const* d_in, const int* in_sizes, int n_in,
                              void* d_out, int out_size, void* d_ws, size_t ws_size,
                              hipStream_t stream) {
    const float* Q = (const float*)d_in[0];
    const float* K = (const float*)d_in[1];
    const float* V = (const float*)d_in[2];
    float* O = (float*)d_out;

    unsigned short* Kb = (unsigned short*)d_ws;   // 16 MB bf16 K
    unsigned short* Vt = Kb + (size_t)NELEM;      // 16 MB bf16 V^T

    prep_kv<<<dim3(SEQ / 64, NBH), 256, 0, stream>>>(K, V, Kb, Vt);
    fa_fwd<<<dim3((SEQ / BM) * NBH), dim3(256), 0, stream>>>(Q, Kb, Vt, O);
}